// Round 3
// baseline (49.720 us; speedup 1.0000x reference)
//
#include <hip/hip_runtime.h>

// roi_align_inv, gather formulation, per-ROI separable precompute + zero-skip.
// One block per ROI:
//   Phase A: per-column u-weights/indices (168 divs) + per-row v-info (168 divs)
//   Phase B: cinterp[7][168] = x-interpolated pool rows
//   Phase C: streaming store; rows with both v-weights == 0 store zeros directly
//            (bitwise-equal: 0*a + 0*b == +-0, |err| == 0), nontemporal stores.

#define MAP_H 168
#define MAP_W 168
#define POOLW 7
#define HW (MAP_H * MAP_W)        // 28224
#define QUADS (HW / 4)            // 7056
#define QROW (MAP_W / 4)          // 42

typedef float f32x4 __attribute__((ext_vector_type(4)));

__global__ __launch_bounds__(256) void roi_inv_kernel(
    const float* __restrict__ pool_dams,   // [N,7,7]
    const float* __restrict__ rois,        // [N,4]
    float* __restrict__ out)               // [N,168,168]
{
    const int n   = blockIdx.x;
    const int tid = threadIdx.x;

    __shared__ float  pf[49];
    __shared__ float  cw0[MAP_W], cw1[MAP_W];
    __shared__ int    cpk[MAP_W];
    __shared__ f32x4  rowt[MAP_H];               // {rw0, rw1, qoff_l(bits), qoff_h(bits)}
    __shared__ float  cinterp[POOLW * MAP_W];    // [7][168]

    if (tid < 49) pf[tid] = pool_dams[n * 49 + tid];

    const float x1 = fminf(fmaxf(rois[n * 4 + 0], 0.0f), (float)(MAP_W - 1));
    const float y1 = fminf(fmaxf(rois[n * 4 + 1], 0.0f), (float)(MAP_H - 1));
    const float x2 = fminf(fmaxf(rois[n * 4 + 2], 0.0f), (float)(MAP_W - 1));
    const float y2 = fminf(fmaxf(rois[n * 4 + 3], 0.0f), (float)(MAP_H - 1));
    const float dw = x2 - x1;
    const float dh = y2 - y1;

    if (tid < MAP_W) {
        // ---- column (x) entry: exact reference op order (gx - x1)/dw * 6 ----
        {
            const float u  = ((float)tid - x1) / dw * 6.0f;
            const float ul = floorf(u), uh = ceilf(u);
            const bool  uvalid = (ul >= 0.0f) && (uh < (float)POOLW);
            const float xw = u - ul;
            const int ixl = min(max((int)ul, 0), POOLW - 1);
            const int ixh = min(max((int)uh, 0), POOLW - 1);
            cw0[tid] = uvalid ? (1.0f - xw) : 0.0f;
            cw1[tid] = uvalid ? xw          : 0.0f;
            cpk[tid] = ixl | (ixh << 8);
        }
        // ---- row (y) entry ----
        {
            const float v  = ((float)tid - y1) / dh * 6.0f;
            const float vl = floorf(v), vh = ceilf(v);
            const bool  vvalid = (vl >= 0.0f) && (vh < (float)POOLW);
            const float yw = v - vl;
            const int iyl = min(max((int)vl, 0), POOLW - 1);
            const int iyh = min(max((int)vh, 0), POOLW - 1);
            f32x4 rt;
            rt[0] = vvalid ? (1.0f - yw) : 0.0f;
            rt[1] = vvalid ? yw          : 0.0f;
            rt[2] = __int_as_float(iyl * QROW);   // f32x4-element offset into cinterp
            rt[3] = __int_as_float(iyh * QROW);
            rowt[tid] = rt;
        }
    }
    __syncthreads();

    if (tid < MAP_W) {
        const float w0 = cw0[tid];
        const float w1 = cw1[tid];
        const int   pk = cpk[tid];
        const int ixl = pk & 0xff;
        const int ixh = pk >> 8;
#pragma unroll
        for (int r = 0; r < POOLW; ++r)
            cinterp[r * MAP_W + tid] = pf[r * POOLW + ixl] * w0 + pf[r * POOLW + ixh] * w1;
    }
    __syncthreads();

    const f32x4* ci = (const f32x4*)cinterp;     // 168*4B rows -> 42 f32x4 per row
    f32x4* op = (f32x4*)(out + (size_t)n * HW);

    int y  = tid / QROW;
    int xq = tid - y * QROW;
#pragma unroll 4
    for (int qi = tid; qi < QUADS; qi += 256) {
        const f32x4 rt = rowt[y];
        f32x4 r = (f32x4)0.0f;
        if (rt[0] != 0.0f || rt[1] != 0.0f) {
            const f32x4 a = ci[__float_as_int(rt[2]) + xq];
            const f32x4 b = ci[__float_as_int(rt[3]) + xq];
            r = a * rt[0] + b * rt[1];
        }
        __builtin_nontemporal_store(r, op + qi);
        // advance by 256 quads: 256 = 6*42 + 4
        y += 6; xq += 4;
        if (xq >= QROW) { xq -= QROW; ++y; }
    }
}

extern "C" void kernel_launch(void* const* d_in, const int* in_sizes, int n_in,
                              void* d_out, int out_size, void* d_ws, size_t ws_size,
                              hipStream_t stream) {
    const float* pool_dams = (const float*)d_in[0];
    const float* rois      = (const float*)d_in[1];
    float* out = (float*)d_out;

    const int n_rois = in_sizes[0] / 49;   // 2048
    roi_inv_kernel<<<dim3(n_rois), 256, 0, stream>>>(pool_dams, rois, out);
}

// Round 4
// 35.721 us; speedup vs baseline: 1.3919x; 1.3919x over previous
//
#include <hip/hip_runtime.h>

// roi_align_inv, gather formulation, per-ROI separable precompute + zero-skip.
// One block per ROI:
//   Phase A: per-column u-weights/indices (168 divs) + per-row v-info (168 divs)
//   Phase B: cinterp[7][168] = x-interpolated pool rows
//   Phase C: streaming store; rows with both v-weights == 0 store zeros directly
//            (bitwise-equal: 0*a + 0*b == +-0). PLAIN stores (nt regressed r3:
//            39.1 -> 49.7 us; L2 write-combining is needed for full-line HBM writes).

#define MAP_H 168
#define MAP_W 168
#define POOLW 7
#define HW (MAP_H * MAP_W)        // 28224
#define QUADS (HW / 4)            // 7056
#define QROW (MAP_W / 4)          // 42

typedef float f32x4 __attribute__((ext_vector_type(4)));

__global__ __launch_bounds__(256) void roi_inv_kernel(
    const float* __restrict__ pool_dams,   // [N,7,7]
    const float* __restrict__ rois,        // [N,4]
    float* __restrict__ out)               // [N,168,168]
{
    const int n   = blockIdx.x;
    const int tid = threadIdx.x;

    __shared__ float  pf[49];
    __shared__ float  cw0[MAP_W], cw1[MAP_W];
    __shared__ int    cpk[MAP_W];
    __shared__ f32x4  rowt[MAP_H];               // {rw0, rw1, qoff_l(bits), qoff_h(bits)}
    __shared__ float  cinterp[POOLW * MAP_W];    // [7][168]

    if (tid < 49) pf[tid] = pool_dams[n * 49 + tid];

    const float x1 = fminf(fmaxf(rois[n * 4 + 0], 0.0f), (float)(MAP_W - 1));
    const float y1 = fminf(fmaxf(rois[n * 4 + 1], 0.0f), (float)(MAP_H - 1));
    const float x2 = fminf(fmaxf(rois[n * 4 + 2], 0.0f), (float)(MAP_W - 1));
    const float y2 = fminf(fmaxf(rois[n * 4 + 3], 0.0f), (float)(MAP_H - 1));
    const float dw = x2 - x1;
    const float dh = y2 - y1;

    if (tid < MAP_W) {
        // ---- column (x) entry: exact reference op order (gx - x1)/dw * 6 ----
        {
            const float u  = ((float)tid - x1) / dw * 6.0f;
            const float ul = floorf(u), uh = ceilf(u);
            const bool  uvalid = (ul >= 0.0f) && (uh < (float)POOLW);
            const float xw = u - ul;
            const int ixl = min(max((int)ul, 0), POOLW - 1);
            const int ixh = min(max((int)uh, 0), POOLW - 1);
            cw0[tid] = uvalid ? (1.0f - xw) : 0.0f;
            cw1[tid] = uvalid ? xw          : 0.0f;
            cpk[tid] = ixl | (ixh << 8);
        }
        // ---- row (y) entry ----
        {
            const float v  = ((float)tid - y1) / dh * 6.0f;
            const float vl = floorf(v), vh = ceilf(v);
            const bool  vvalid = (vl >= 0.0f) && (vh < (float)POOLW);
            const float yw = v - vl;
            const int iyl = min(max((int)vl, 0), POOLW - 1);
            const int iyh = min(max((int)vh, 0), POOLW - 1);
            f32x4 rt;
            rt[0] = vvalid ? (1.0f - yw) : 0.0f;
            rt[1] = vvalid ? yw          : 0.0f;
            rt[2] = __int_as_float(iyl * QROW);   // f32x4-element offset into cinterp
            rt[3] = __int_as_float(iyh * QROW);
            rowt[tid] = rt;
        }
    }
    __syncthreads();

    if (tid < MAP_W) {
        const float w0 = cw0[tid];
        const float w1 = cw1[tid];
        const int   pk = cpk[tid];
        const int ixl = pk & 0xff;
        const int ixh = pk >> 8;
#pragma unroll
        for (int r = 0; r < POOLW; ++r)
            cinterp[r * MAP_W + tid] = pf[r * POOLW + ixl] * w0 + pf[r * POOLW + ixh] * w1;
    }
    __syncthreads();

    const f32x4* ci = (const f32x4*)cinterp;     // 42 f32x4 per row
    f32x4* op = (f32x4*)(out + (size_t)n * HW);

    int y  = tid / QROW;
    int xq = tid - y * QROW;
#pragma unroll 4
    for (int qi = tid; qi < QUADS; qi += 256) {
        const f32x4 rt = rowt[y];
        f32x4 r = (f32x4)0.0f;
        if (rt[0] != 0.0f || rt[1] != 0.0f) {
            const f32x4 a = ci[__float_as_int(rt[2]) + xq];
            const f32x4 b = ci[__float_as_int(rt[3]) + xq];
            r = a * rt[0] + b * rt[1];
        }
        op[qi] = r;
        // advance by 256 quads: 256 = 6*42 + 4
        y += 6; xq += 4;
        if (xq >= QROW) { xq -= QROW; ++y; }
    }
}

extern "C" void kernel_launch(void* const* d_in, const int* in_sizes, int n_in,
                              void* d_out, int out_size, void* d_ws, size_t ws_size,
                              hipStream_t stream) {
    const float* pool_dams = (const float*)d_in[0];
    const float* rois      = (const float*)d_in[1];
    float* out = (float*)d_out;

    const int n_rois = in_sizes[0] / 49;   // 2048
    roi_inv_kernel<<<dim3(n_rois), 256, 0, stream>>>(pool_dams, rois, out);
}